// Round 5
// baseline (192.398 us; speedup 1.0000x reference)
//
#include <hip/hip_runtime.h>
#include <math.h>

constexpr int Bb = 2;
constexpr int Nn = 2048;
constexpr int Cc = 512;
constexpr int Hh = 8;
constexpr int Dd = 64;

typedef short short8 __attribute__((ext_vector_type(8)));
typedef float floatx4 __attribute__((ext_vector_type(4)));
typedef float floatx16 __attribute__((ext_vector_type(16)));

__device__ inline short8 bcs8(uint4 u) { return __builtin_bit_cast(short8, u); }

__device__ inline floatx4 mfma16(short8 a, short8 b, floatx4 c) {
    return __builtin_amdgcn_mfma_f32_16x16x32_bf16(a, b, c, 0, 0, 0);
}
__device__ inline floatx16 mfma32(short8 a, short8 b, floatx16 c) {
    return __builtin_amdgcn_mfma_f32_32x32x16_bf16(a, b, c, 0, 0, 0);
}

// async global->LDS, 16B per lane, dest = uniform base + lane*16
typedef __attribute__((address_space(1))) void gvoid;
typedef __attribute__((address_space(3))) void svoid;
__device__ inline void glds16(const void* g, void* l) {
    __builtin_amdgcn_global_load_lds((const gvoid*)g, (svoid*)l, 16, 0, 0);
}

#if __has_builtin(__builtin_amdgcn_exp2f)
#define EXP2(x) __builtin_amdgcn_exp2f(x)
#else
#define EXP2(x) __expf((x) * 0.69314718056f)
#endif

// pack bf16(a)|bf16(b)<<16, truncation (hi/lo splits: lo compensates hi)
__device__ inline unsigned pk_trunc(float a, float b) {
    return __builtin_amdgcn_perm(__float_as_uint(b), __float_as_uint(a), 0x07060302u);
}
// RNE pack
__device__ inline unsigned pk_rne(float a, float b) {
    unsigned ua = __float_as_uint(a); ua += 0x7fffu + ((ua >> 16) & 1u);
    unsigned ub = __float_as_uint(b); ub += 0x7fffu + ((ub >> 16) & 1u);
    return __builtin_amdgcn_perm(ub, ua, 0x07060302u);
}
__device__ inline unsigned short rne1(float a) {
    unsigned u = __float_as_uint(a); u += 0x7fffu + ((u >> 16) & 1u);
    return (unsigned short)(u >> 16);
}
__device__ inline float tr16(float a) {
    return __uint_as_float(__float_as_uint(a) & 0xffff0000u);
}
__device__ inline void split8(float4 A, float4 B, uint4& hi, uint4& lo) {
    hi = make_uint4(pk_trunc(A.x, A.y), pk_trunc(A.z, A.w),
                    pk_trunc(B.x, B.y), pk_trunc(B.z, B.w));
    lo = make_uint4(pk_trunc(A.x - tr16(A.x), A.y - tr16(A.y)),
                    pk_trunc(A.z - tr16(A.z), A.w - tr16(A.w)),
                    pk_trunc(B.x - tr16(B.x), B.y - tr16(B.y)),
                    pk_trunc(B.z - tr16(B.z), B.w - tr16(B.w)));
}

// ---------------------------------------------------------------------------
// Fused prep: bid<256 -> weight transpose+split (wprep); bid>=256 -> x split.
// ---------------------------------------------------------------------------
__global__ __launch_bounds__(256) void prep(const float* __restrict__ qkv_w,
                                            const float* __restrict__ proj_w,
                                            const float* __restrict__ x,
                                            unsigned short* __restrict__ wqh,
                                            unsigned short* __restrict__ wql,
                                            unsigned short* __restrict__ wph,
                                            unsigned short* __restrict__ wpl,
                                            unsigned short* __restrict__ xh,
                                            unsigned short* __restrict__ xl)
{
    __shared__ float Tl[64][68];
    int bid = blockIdx.x;
    if (bid >= 256) {                      // ---- x split ----
        size_t base = ((size_t)(bid - 256) * 256 + threadIdx.x) * 16;
        float4 a = *(const float4*)(x + base);
        float4 b = *(const float4*)(x + base + 4);
        float4 c = *(const float4*)(x + base + 8);
        float4 d = *(const float4*)(x + base + 12);
        uint4 h0, L0, h1, L1;
        split8(a, b, h0, L0); split8(c, d, h1, L1);
        *(uint4*)(xh + base) = h0; *(uint4*)(xh + base + 8) = h1;
        *(uint4*)(xl + base) = L0; *(uint4*)(xl + base + 8) = L1;
        return;
    }
    // ---- weight transpose + split ----
    const float* src; unsigned short *dh, *dlo; int W, f0, k0;
    if (bid < 192) { int kt = bid / 24, ft = bid % 24; W = 1536; src = qkv_w; dh = wqh; dlo = wql; f0 = ft * 64; k0 = kt * 64; }
    else { int b2 = bid - 192; int kt = b2 / 8, ft = b2 % 8; W = 512; src = proj_w; dh = wph; dlo = wpl; f0 = ft * 64; k0 = kt * 64; }
    int t = threadIdx.x;
    {
        int kl = t >> 2, fc = (t & 3) * 16;
        const float* p = src + (size_t)(k0 + kl) * W + f0 + fc;
        #pragma unroll
        for (int i = 0; i < 4; ++i) {
            float4 v = *(const float4*)(p + i * 4);
            Tl[kl][fc + i * 4 + 0] = v.x; Tl[kl][fc + i * 4 + 1] = v.y;
            Tl[kl][fc + i * 4 + 2] = v.z; Tl[kl][fc + i * 4 + 3] = v.w;
        }
    }
    __syncthreads();
    {
        int fl = t >> 2, kc = (t & 3) * 16;
        float v[16];
        #pragma unroll
        for (int i = 0; i < 16; ++i) v[i] = Tl[kc + i][fl];
        unsigned hi[8], lo[8];
        #pragma unroll
        for (int i = 0; i < 8; ++i) {
            float a = v[2 * i], b = v[2 * i + 1];
            hi[i] = pk_trunc(a, b);
            lo[i] = pk_trunc(a - tr16(a), b - tr16(b));
        }
        unsigned short* oh = dh + (size_t)(f0 + fl) * 512 + k0 + kc;
        unsigned short* ol = dlo + (size_t)(f0 + fl) * 512 + k0 + kc;
        *(uint4*)oh = make_uint4(hi[0], hi[1], hi[2], hi[3]);
        *(uint4*)(oh + 8) = make_uint4(hi[4], hi[5], hi[6], hi[7]);
        *(uint4*)ol = make_uint4(lo[0], lo[1], lo[2], lo[3]);
        *(uint4*)(ol + 8) = make_uint4(lo[4], lo[5], lo[6], lo[7]);
    }
}

// ---------------------------------------------------------------------------
// GEMM1: x(split) @ qkv_w(split,T) -> dense qd/kd[bh][n][64] + vt[bh][d][n].
// q pre-scaled by 0.125*log2(e). BM=128 BN=64 BK=64, 256 thr, grid (24,32).
// ---------------------------------------------------------------------------
__global__ __launch_bounds__(256, 3) void gemm_qkv(const unsigned short* __restrict__ xh,
                                                   const unsigned short* __restrict__ xl,
                                                   const unsigned short* __restrict__ wh,
                                                   const unsigned short* __restrict__ wl,
                                                   unsigned short* __restrict__ qd,
                                                   unsigned short* __restrict__ kd,
                                                   unsigned short* __restrict__ vt)
{
    __shared__ __align__(16) char smem[49152];
    char* Ah = smem; char* Al = smem + 16384; char* Bh = smem + 32768; char* Bl = smem + 40960;
    const int tid = threadIdx.x, lane = tid & 63, w = tid >> 6;
    const int l15 = lane & 15, l4 = lane >> 4;
    const int row0 = blockIdx.y * 128, col0 = blockIdx.x * 64;
    const int wm = w >> 1, wn = w & 1;

    floatx4 acc[4][2];
    #pragma unroll
    for (int i = 0; i < 4; ++i)
        #pragma unroll
        for (int j = 0; j < 2; ++j)
            #pragma unroll
            for (int r = 0; r < 4; ++r) acc[i][j][r] = 0.f;

    for (int k0 = 0; k0 < 512; k0 += 64) {
        #pragma unroll
        for (int i = 0; i < 8; ++i) {            // A: 32 segs (mt8 x kk2 x comp2)
            int sid = w * 8 + i; int comp = sid & 1, kk = (sid >> 1) & 1, mt = sid >> 2;
            const unsigned short* src = (comp ? xl : xh) + (size_t)(row0 + mt * 16 + l15) * 512 + k0 + kk * 32 + l4 * 8;
            glds16(src, (comp ? Al : Ah) + (mt * 2 + kk) * 1024);
        }
        #pragma unroll
        for (int i = 0; i < 4; ++i) {            // B: 16 segs (nt4 x kk2 x comp2)
            int sid = w * 4 + i; int comp = sid & 1, kk = (sid >> 1) & 1, nt = sid >> 2;
            const unsigned short* src = (comp ? wl : wh) + (size_t)(col0 + nt * 16 + l15) * 512 + k0 + kk * 32 + l4 * 8;
            glds16(src, (comp ? Bl : Bh) + (nt * 2 + kk) * 1024);
        }
        __syncthreads();
        #pragma unroll
        for (int kk = 0; kk < 2; ++kk) {
            short8 af[4][2], bf[2][2];
            #pragma unroll
            for (int mt = 0; mt < 4; ++mt) {
                int off = (((wm * 4 + mt) * 2 + kk) << 10) + (lane << 4);
                af[mt][0] = bcs8(*(const uint4*)(Ah + off));
                af[mt][1] = bcs8(*(const uint4*)(Al + off));
            }
            #pragma unroll
            for (int nt = 0; nt < 2; ++nt) {
                int off = (((wn * 2 + nt) * 2 + kk) << 10) + (lane << 4);
                bf[nt][0] = bcs8(*(const uint4*)(Bh + off));
                bf[nt][1] = bcs8(*(const uint4*)(Bl + off));
            }
            #pragma unroll
            for (int mt = 0; mt < 4; ++mt)
                #pragma unroll
                for (int nt = 0; nt < 2; ++nt) {
                    acc[mt][nt] = mfma16(af[mt][0], bf[nt][0], acc[mt][nt]);
                    acc[mt][nt] = mfma16(af[mt][0], bf[nt][1], acc[mt][nt]);
                    acc[mt][nt] = mfma16(af[mt][1], bf[nt][0], acc[mt][nt]);
                }
        }
        __syncthreads();
    }
    // epilogue: q (scaled, with log2e folded), k dense; v written transposed
    #pragma unroll
    for (int mt = 0; mt < 4; ++mt)
        #pragma unroll
        for (int nt = 0; nt < 2; ++nt) {
            int c = col0 + (wn * 2 + nt) * 16 + l15;     // 0..1535
            int which = c >> 9;                          // 0=q,1=k,2=v (block-uniform)
            int head = (c >> 6) & 7, d = c & 63;
            int tokb = row0 + (wm * 4 + mt) * 16 + l4 * 4;
            int b = tokb >> 11, n = tokb & 2047;
            if (which == 2) {
                uint2 pv;
                pv.x = pk_rne(acc[mt][nt][0], acc[mt][nt][1]);
                pv.y = pk_rne(acc[mt][nt][2], acc[mt][nt][3]);
                *(uint2*)&vt[((size_t)((b * 8 + head) * 64 + d)) * 2048 + n] = pv;
            } else {
                unsigned short* dst = which ? kd : qd;
                float s = which ? 1.0f : 0.18033688f;    // 0.125 * log2(e)
                #pragma unroll
                for (int r = 0; r < 4; ++r)
                    dst[(size_t)((b * 8 + head) * 2048 + n + r) * 64 + d] = rne1(acc[mt][nt][r] * s);
            }
        }
}

// ---------------------------------------------------------------------------
// Attention: barrier-free K-loop. Block = 32 q x 4 kg-waves (256 thr).
// Grid 1024 = 16 bh x 64 qtiles (XCD-swizzled). Each wave owns a contiguous
// 512-key strip, loads K/V fragments straight from global (kf double-
// buffered in registers), S^T = K.Q^T with exp2 (log2e pre-folded into Q),
// P via half-swap shuffle, PV accumulate; single LDS merge at the end.
// ---------------------------------------------------------------------------
__global__ __launch_bounds__(256, 3) void attn(const unsigned short* __restrict__ qd,
                                               const unsigned short* __restrict__ kd,
                                               const unsigned short* __restrict__ vt,
                                               unsigned short* __restrict__ Oh,
                                               unsigned short* __restrict__ Ol)
{
    __shared__ float Ms[2048];     // [d(64)][q(32)]
    __shared__ float Ls[64];       // [h(2)][q(32)]
    __shared__ float Ts[2176];     // [q(32)][68]

    int bid = blockIdx.x;
    int xcd = bid & 7; int rr = bid >> 3;
    int qt = rr & 63; int bhi = rr >> 6;
    int bh = (bhi << 3) | xcd;
    int tid = threadIdx.x, lane = tid & 63, kg = tid >> 6;
    int l31 = lane & 31, h = lane >> 5;

    // Q^T fragments (B-operand), once from dense qd (pre-scaled, log2e folded)
    short8 qf[4];
    #pragma unroll
    for (int s = 0; s < 4; ++s)
        qf[s] = bcs8(*(const uint4*)(qd + ((size_t)bh * 2048 + qt * 32 + l31) * 64 + s * 16 + h * 8));

    floatx16 OT[2];
    #pragma unroll
    for (int i = 0; i < 2; ++i)
        #pragma unroll
        for (int r = 0; r < 16; ++r) OT[i][r] = 0.f;
    float lacc = 0.f;

    // per-lane base pointers for this wave's 512-key strip
    const unsigned short* kb_ = kd + ((size_t)bh * 2048 + kg * 512 + l31) * 64 + h * 8;
    const unsigned short* vb_ = vt + ((size_t)bh * 64 + l31) * 2048 + kg * 512 + h * 8;

    uint4 kf[2][4];                 // K frags, register double-buffered
    #pragma unroll
    for (int s = 0; s < 4; ++s) kf[0][s] = *(const uint4*)(kb_ + s * 16);

    #pragma unroll
    for (int c = 0; c < 16; ++c) {
        const int cur = c & 1;
        // prefetch next chunk's K frags
        if (c < 15) {
            const unsigned short* kp = kb_ + (size_t)(c + 1) * 2048;
            #pragma unroll
            for (int s = 0; s < 4; ++s) kf[cur ^ 1][s] = *(const uint4*)(kp + s * 16);
        }
        // V^T frags for this chunk (issued here, used after QK+exp)
        uint4 vf[4];
        {
            const unsigned short* vp = vb_ + c * 32;
            #pragma unroll
            for (int j = 0; j < 4; ++j)
                vf[j] = *(const uint4*)(vp + (j >> 1) * 65536 + (j & 1) * 16);
        }

        floatx16 st;
        #pragma unroll
        for (int r = 0; r < 16; ++r) st[r] = 0.f;
        #pragma unroll
        for (int s = 0; s < 4; ++s) st = mfma32(bcs8(kf[cur][s]), qf[s], st);

        unsigned P2[8]; float ssum = 0.f;
        #pragma unroll
        for (int s2 = 0; s2 < 8; ++s2) {
            float e0 = EXP2(st[2 * s2]), e1 = EXP2(st[2 * s2 + 1]);
            ssum += e0 + e1;
            P2[s2] = pk_rne(e0, e1);
        }
        lacc += ssum;

        #pragma unroll
        for (int kc = 0; kc < 2; ++kc) {
            unsigned X0 = P2[4 * kc + 0], X1 = P2[4 * kc + 1];
            unsigned Y0 = P2[4 * kc + 2], Y1 = P2[4 * kc + 3];
            unsigned Xo0 = __shfl_xor(X0, 32, 64), Xo1 = __shfl_xor(X1, 32, 64);
            unsigned Yo0 = __shfl_xor(Y0, 32, 64), Yo1 = __shfl_xor(Y1, 32, 64);
            uint4 fu;
            fu.x = h ? Yo0 : X0;
            fu.y = h ? Yo1 : X1;
            fu.z = h ? Y0 : Xo0;
            fu.w = h ? Y1 : Xo1;
            short8 pf = bcs8(fu);
            OT[0] = mfma32(bcs8(vf[kc]), pf, OT[0]);
            OT[1] = mfma32(bcs8(vf[2 + kc]), pf, OT[1]);
        }
    }

    // ---- merge partial O/l across the 4 kg waves (end-of-kernel only) ----
    if (kg == 3) {
        #pragma unroll
        for (int mtv = 0; mtv < 2; ++mtv)
            #pragma unroll
            for (int r = 0; r < 16; ++r) {
                int d = mtv * 32 + (r & 3) + 8 * (r >> 2) + 4 * h;
                Ms[d * 32 + l31] = OT[mtv][r];
            }
        Ls[h * 32 + l31] = lacc;
    }
    __syncthreads();
    if (kg == 2) {
        #pragma unroll
        for (int mtv = 0; mtv < 2; ++mtv)
            #pragma unroll
            for (int r = 0; r < 16; ++r) {
                int d = mtv * 32 + (r & 3) + 8 * (r >> 2) + 4 * h;
                Ms[d * 32 + l31] += OT[mtv][r];
            }
        Ls[h * 32 + l31] += lacc;
    }
    __syncthreads();
    if (kg == 1) {
        #pragma unroll
        for (int mtv = 0; mtv < 2; ++mtv)
            #pragma unroll
            for (int r = 0; r < 16; ++r) {
                int d = mtv * 32 + (r & 3) + 8 * (r >> 2) + 4 * h;
                Ms[d * 32 + l31] += OT[mtv][r];
            }
        Ls[h * 32 + l31] += lacc;
    }
    __syncthreads();
    if (kg == 0) {
        #pragma unroll
        for (int mtv = 0; mtv < 2; ++mtv)
            #pragma unroll
            for (int r = 0; r < 16; ++r) {
                int d = mtv * 32 + (r & 3) + 8 * (r >> 2) + 4 * h;
                OT[mtv][r] += Ms[d * 32 + l31];
            }
        Ls[h * 32 + l31] += lacc;
    }
    __syncthreads();
    if (kg == 0) {
        float inv = 1.f / (Ls[l31] + Ls[32 + l31]);
        #pragma unroll
        for (int mtv = 0; mtv < 2; ++mtv)
            #pragma unroll
            for (int r = 0; r < 16; ++r) {
                int d = mtv * 32 + (r & 3) + 8 * (r >> 2) + 4 * h;
                Ts[l31 * 68 + d] = OT[mtv][r] * inv;
            }
    }
    __syncthreads();
    // all 256 threads: coalesced split-bf16 store of O (flat B,H,N,D)
    {
        int q = tid >> 3, dc = (tid & 7) * 8;
        float vv[8];
        #pragma unroll
        for (int i = 0; i < 8; ++i) vv[i] = Ts[q * 68 + dc + i];
        unsigned hi[4], lo[4];
        #pragma unroll
        for (int i = 0; i < 4; ++i) {
            float a = vv[2 * i], bb = vv[2 * i + 1];
            hi[i] = pk_trunc(a, bb);
            lo[i] = pk_trunc(a - tr16(a), bb - tr16(bb));
        }
        size_t bo = ((size_t)(bh * 2048 + qt * 32 + q)) * 64 + dc;
        *(uint4*)(Oh + bo) = make_uint4(hi[0], hi[1], hi[2], hi[3]);
        *(uint4*)(Ol + bo) = make_uint4(lo[0], lo[1], lo[2], lo[3]);
    }
}

// ---------------------------------------------------------------------------
// GEMM2: out = O(split) @ proj_w(split,T) + bias. BM=64 BN=64 BK=64,
// 256 thr = 4 waves of 32x32. grid (8, 64) = 512 blocks.
// ---------------------------------------------------------------------------
__global__ __launch_bounds__(256, 2) void gemm_proj(const unsigned short* __restrict__ Ah_g,
                                                    const unsigned short* __restrict__ Al_g,
                                                    const unsigned short* __restrict__ wh,
                                                    const unsigned short* __restrict__ wl,
                                                    const float* __restrict__ bias,
                                                    float* __restrict__ out)
{
    __shared__ __align__(16) char smem[32768];
    char* Ah = smem; char* Al = smem + 8192; char* Bh = smem + 16384; char* Bl = smem + 24576;
    const int tid = threadIdx.x, lane = tid & 63, w = tid >> 6;
    const int l15 = lane & 15, l4 = lane >> 4;
    const int row0 = blockIdx.y * 64, col0 = blockIdx.x * 64;
    const int wm = w >> 1, wn = w & 1;

    floatx4 acc[2][2];
    #pragma unroll
    for (int i = 0; i < 2; ++i)
        #pragma unroll
        for (int j = 0; j < 2; ++j)
            #pragma unroll
            for (int r = 0; r < 4; ++r) acc[i][j][r] = 0.f;

    for (int k0 = 0; k0 < 512; k0 += 64) {
        #pragma unroll
        for (int i = 0; i < 8; ++i) {      // 32 segs: 16 A + 16 B
            int sid = w * 8 + i;
            if (sid < 16) {
                int comp = sid & 1, kk = (sid >> 1) & 1, mt = sid >> 2;
                const unsigned short* src = (comp ? Al_g : Ah_g) + (size_t)(row0 + mt * 16 + l15) * 512 + k0 + kk * 32 + l4 * 8;
                glds16(src, (comp ? Al : Ah) + (mt * 2 + kk) * 1024);
            } else {
                int s2 = sid - 16; int comp = s2 & 1, kk = (s2 >> 1) & 1, nt = s2 >> 2;
                const unsigned short* src = (comp ? wl : wh) + (size_t)(col0 + nt * 16 + l15) * 512 + k0 + kk * 32 + l4 * 8;
                glds16(src, (comp ? Bl : Bh) + (nt * 2 + kk) * 1024);
            }
        }
        __syncthreads();
        #pragma unroll
        for (int kk = 0; kk < 2; ++kk) {
            short8 af[2][2], bf[2][2];
            #pragma unroll
            for (int mt = 0; mt < 2; ++mt) {
                int off = (((wm * 2 + mt) * 2 + kk) << 10) + (lane << 4);
                af[mt][0] = bcs8(*(const uint4*)(Ah + off));
                af[mt][1] = bcs8(*(const uint4*)(Al + off));
            }
            #pragma unroll
            for (int nt = 0; nt < 2; ++nt) {
                int off = (((wn * 2 + nt) * 2 + kk) << 10) + (lane << 4);
                bf[nt][0] = bcs8(*(const uint4*)(Bh + off));
                bf[nt][1] = bcs8(*(const uint4*)(Bl + off));
            }
            #pragma unroll
            for (int mt = 0; mt < 2; ++mt)
                #pragma unroll
                for (int nt = 0; nt < 2; ++nt) {
                    acc[mt][nt] = mfma16(af[mt][0], bf[nt][0], acc[mt][nt]);
                    acc[mt][nt] = mfma16(af[mt][0], bf[nt][1], acc[mt][nt]);
                    acc[mt][nt] = mfma16(af[mt][1], bf[nt][0], acc[mt][nt]);
                }
        }
        __syncthreads();
    }
    #pragma unroll
    for (int mt = 0; mt < 2; ++mt)
        #pragma unroll
        for (int nt = 0; nt < 2; ++nt) {
            int c = col0 + (wn * 2 + nt) * 16 + l15;
            float bv = bias[c];
            #pragma unroll
            for (int r = 0; r < 4; ++r) {
                int tok = row0 + (wm * 2 + mt) * 16 + l4 * 4 + r;
                out[(size_t)tok * 512 + c] = acc[mt][nt][r] + bv;
            }
        }
}

// ---------------------------------------------------------------------------
extern "C" void kernel_launch(void* const* d_in, const int* in_sizes, int n_in,
                              void* d_out, int out_size, void* d_ws, size_t ws_size,
                              hipStream_t stream)
{
    const float* x      = (const float*)d_in[0];
    const float* qkv_w  = (const float*)d_in[1];
    const float* proj_w = (const float*)d_in[2];
    const float* proj_b = (const float*)d_in[3];
    float* out = (float*)d_out;

    char* ws = (char*)d_ws;
    unsigned short* qd   = (unsigned short*)ws;                      //  4 MiB
    unsigned short* kd   = (unsigned short*)(ws + 4194304);          //  4 MiB
    unsigned short* vt   = (unsigned short*)(ws + 8388608);          //  4 MiB
    unsigned short* wqh  = (unsigned short*)(ws + 12582912);         // 1.5 MiB
    unsigned short* wql  = (unsigned short*)(ws + 14155776);         // 1.5 MiB
    unsigned short* wph  = (unsigned short*)(ws + 15728640);         // 0.5 MiB
    unsigned short* wpl  = (unsigned short*)(ws + 16252928);         // 0.5 MiB
    unsigned short* Oh   = (unsigned short*)(ws + 16777216);         //  4 MiB
    unsigned short* Ol   = (unsigned short*)(ws + 20971520);         //  4 MiB (end 24 MiB)
    // xh/xl overlay Oh/Ol: consumed by gemm_qkv before attn writes Oh/Ol.
    unsigned short* xh = Oh;
    unsigned short* xl = Ol;

    prep<<<768, 256, 0, stream>>>(qkv_w, proj_w, x, wqh, wql, wph, wpl, xh, xl);
    gemm_qkv<<<dim3(24, 32), 256, 0, stream>>>(xh, xl, wqh, wql, qd, kd, vt);
    attn<<<1024, 256, 0, stream>>>(qd, kd, vt, Oh, Ol);
    gemm_proj<<<dim3(8, 64), 256, 0, stream>>>(Oh, Ol, wph, wpl, proj_b, out);
}

// Round 6
// 170.488 us; speedup vs baseline: 1.1285x; 1.1285x over previous
//
#include <hip/hip_runtime.h>
#include <math.h>

constexpr int Bb = 2;
constexpr int Nn = 2048;
constexpr int Cc = 512;
constexpr int Hh = 8;
constexpr int Dd = 64;

typedef short short8 __attribute__((ext_vector_type(8)));
typedef float floatx4 __attribute__((ext_vector_type(4)));
typedef float floatx16 __attribute__((ext_vector_type(16)));

__device__ inline short8 bcs8(uint4 u) { return __builtin_bit_cast(short8, u); }

__device__ inline floatx4 mfma16(short8 a, short8 b, floatx4 c) {
    return __builtin_amdgcn_mfma_f32_16x16x32_bf16(a, b, c, 0, 0, 0);
}
__device__ inline floatx16 mfma32(short8 a, short8 b, floatx16 c) {
    return __builtin_amdgcn_mfma_f32_32x32x16_bf16(a, b, c, 0, 0, 0);
}

// async global->LDS, 16B per lane, dest = uniform base + lane*16
typedef __attribute__((address_space(1))) void gvoid;
typedef __attribute__((address_space(3))) void svoid;
__device__ inline void glds16(const void* g, void* l) {
    __builtin_amdgcn_global_load_lds((const gvoid*)g, (svoid*)l, 16, 0, 0);
}

#if __has_builtin(__builtin_amdgcn_exp2f)
#define EXP2(x) __builtin_amdgcn_exp2f(x)
#else
#define EXP2(x) __expf((x) * 0.69314718056f)
#endif

// pack bf16(a)|bf16(b)<<16, truncation (hi/lo splits: lo compensates hi)
__device__ inline unsigned pk_trunc(float a, float b) {
    return __builtin_amdgcn_perm(__float_as_uint(b), __float_as_uint(a), 0x07060302u);
}
// RNE pack
__device__ inline unsigned pk_rne(float a, float b) {
    unsigned ua = __float_as_uint(a); ua += 0x7fffu + ((ua >> 16) & 1u);
    unsigned ub = __float_as_uint(b); ub += 0x7fffu + ((ub >> 16) & 1u);
    return __builtin_amdgcn_perm(ub, ua, 0x07060302u);
}
__device__ inline unsigned short rne1(float a) {
    unsigned u = __float_as_uint(a); u += 0x7fffu + ((u >> 16) & 1u);
    return (unsigned short)(u >> 16);
}
__device__ inline float tr16(float a) {
    return __uint_as_float(__float_as_uint(a) & 0xffff0000u);
}
__device__ inline void split8(float4 A, float4 B, uint4& hi, uint4& lo) {
    hi = make_uint4(pk_trunc(A.x, A.y), pk_trunc(A.z, A.w),
                    pk_trunc(B.x, B.y), pk_trunc(B.z, B.w));
    lo = make_uint4(pk_trunc(A.x - tr16(A.x), A.y - tr16(A.y)),
                    pk_trunc(A.z - tr16(A.z), A.w - tr16(A.w)),
                    pk_trunc(B.x - tr16(B.x), B.y - tr16(B.y)),
                    pk_trunc(B.z - tr16(B.z), B.w - tr16(B.w)));
}

// ---------------------------------------------------------------------------
// Fused prep: bid<256 -> weight transpose+split; bid>=256 -> x split.
// ---------------------------------------------------------------------------
__global__ __launch_bounds__(256) void prep(const float* __restrict__ qkv_w,
                                            const float* __restrict__ proj_w,
                                            const float* __restrict__ x,
                                            unsigned short* __restrict__ wqh,
                                            unsigned short* __restrict__ wql,
                                            unsigned short* __restrict__ wph,
                                            unsigned short* __restrict__ wpl,
                                            unsigned short* __restrict__ xh,
                                            unsigned short* __restrict__ xl)
{
    __shared__ float Tl[64][68];
    int bid = blockIdx.x;
    if (bid >= 256) {                      // ---- x split ----
        size_t base = ((size_t)(bid - 256) * 256 + threadIdx.x) * 16;
        float4 a = *(const float4*)(x + base);
        float4 b = *(const float4*)(x + base + 4);
        float4 c = *(const float4*)(x + base + 8);
        float4 d = *(const float4*)(x + base + 12);
        uint4 h0, L0, h1, L1;
        split8(a, b, h0, L0); split8(c, d, h1, L1);
        *(uint4*)(xh + base) = h0; *(uint4*)(xh + base + 8) = h1;
        *(uint4*)(xl + base) = L0; *(uint4*)(xl + base + 8) = L1;
        return;
    }
    // ---- weight transpose + split ----
    const float* src; unsigned short *dh, *dlo; int W, f0, k0;
    if (bid < 192) { int kt = bid / 24, ft = bid % 24; W = 1536; src = qkv_w; dh = wqh; dlo = wql; f0 = ft * 64; k0 = kt * 64; }
    else { int b2 = bid - 192; int kt = b2 / 8, ft = b2 % 8; W = 512; src = proj_w; dh = wph; dlo = wpl; f0 = ft * 64; k0 = kt * 64; }
    int t = threadIdx.x;
    {
        int kl = t >> 2, fc = (t & 3) * 16;
        const float* p = src + (size_t)(k0 + kl) * W + f0 + fc;
        #pragma unroll
        for (int i = 0; i < 4; ++i) {
            float4 v = *(const float4*)(p + i * 4);
            Tl[kl][fc + i * 4 + 0] = v.x; Tl[kl][fc + i * 4 + 1] = v.y;
            Tl[kl][fc + i * 4 + 2] = v.z; Tl[kl][fc + i * 4 + 3] = v.w;
        }
    }
    __syncthreads();
    {
        int fl = t >> 2, kc = (t & 3) * 16;
        float v[16];
        #pragma unroll
        for (int i = 0; i < 16; ++i) v[i] = Tl[kc + i][fl];
        unsigned hi[8], lo[8];
        #pragma unroll
        for (int i = 0; i < 8; ++i) {
            float a = v[2 * i], b = v[2 * i + 1];
            hi[i] = pk_trunc(a, b);
            lo[i] = pk_trunc(a - tr16(a), b - tr16(b));
        }
        unsigned short* oh = dh + (size_t)(f0 + fl) * 512 + k0 + kc;
        unsigned short* ol = dlo + (size_t)(f0 + fl) * 512 + k0 + kc;
        *(uint4*)oh = make_uint4(hi[0], hi[1], hi[2], hi[3]);
        *(uint4*)(oh + 8) = make_uint4(hi[4], hi[5], hi[6], hi[7]);
        *(uint4*)ol = make_uint4(lo[0], lo[1], lo[2], lo[3]);
        *(uint4*)(ol + 8) = make_uint4(lo[4], lo[5], lo[6], lo[7]);
    }
}

// ---------------------------------------------------------------------------
// GEMM1: x(split) @ qkv_w(split,T) -> dense qd/kd[bh][n][64] + vt[bh][d][n].
// q pre-scaled by 0.125*log2(e). BM=128 BN=64 BK=64, 256 thr, grid (24,32).
// ---------------------------------------------------------------------------
__global__ __launch_bounds__(256, 3) void gemm_qkv(const unsigned short* __restrict__ xh,
                                                   const unsigned short* __restrict__ xl,
                                                   const unsigned short* __restrict__ wh,
                                                   const unsigned short* __restrict__ wl,
                                                   unsigned short* __restrict__ qd,
                                                   unsigned short* __restrict__ kd,
                                                   unsigned short* __restrict__ vt)
{
    __shared__ __align__(16) char smem[49152];
    char* Ah = smem; char* Al = smem + 16384; char* Bh = smem + 32768; char* Bl = smem + 40960;
    const int tid = threadIdx.x, lane = tid & 63, w = tid >> 6;
    const int l15 = lane & 15, l4 = lane >> 4;
    const int row0 = blockIdx.y * 128, col0 = blockIdx.x * 64;
    const int wm = w >> 1, wn = w & 1;

    floatx4 acc[4][2];
    #pragma unroll
    for (int i = 0; i < 4; ++i)
        #pragma unroll
        for (int j = 0; j < 2; ++j)
            #pragma unroll
            for (int r = 0; r < 4; ++r) acc[i][j][r] = 0.f;

    for (int k0 = 0; k0 < 512; k0 += 64) {
        #pragma unroll
        for (int i = 0; i < 8; ++i) {            // A: 32 segs (mt8 x kk2 x comp2)
            int sid = w * 8 + i; int comp = sid & 1, kk = (sid >> 1) & 1, mt = sid >> 2;
            const unsigned short* src = (comp ? xl : xh) + (size_t)(row0 + mt * 16 + l15) * 512 + k0 + kk * 32 + l4 * 8;
            glds16(src, (comp ? Al : Ah) + (mt * 2 + kk) * 1024);
        }
        #pragma unroll
        for (int i = 0; i < 4; ++i) {            // B: 16 segs (nt4 x kk2 x comp2)
            int sid = w * 4 + i; int comp = sid & 1, kk = (sid >> 1) & 1, nt = sid >> 2;
            const unsigned short* src = (comp ? wl : wh) + (size_t)(col0 + nt * 16 + l15) * 512 + k0 + kk * 32 + l4 * 8;
            glds16(src, (comp ? Bl : Bh) + (nt * 2 + kk) * 1024);
        }
        __syncthreads();
        #pragma unroll
        for (int kk = 0; kk < 2; ++kk) {
            short8 af[4][2], bf[2][2];
            #pragma unroll
            for (int mt = 0; mt < 4; ++mt) {
                int off = (((wm * 4 + mt) * 2 + kk) << 10) + (lane << 4);
                af[mt][0] = bcs8(*(const uint4*)(Ah + off));
                af[mt][1] = bcs8(*(const uint4*)(Al + off));
            }
            #pragma unroll
            for (int nt = 0; nt < 2; ++nt) {
                int off = (((wn * 2 + nt) * 2 + kk) << 10) + (lane << 4);
                bf[nt][0] = bcs8(*(const uint4*)(Bh + off));
                bf[nt][1] = bcs8(*(const uint4*)(Bl + off));
            }
            #pragma unroll
            for (int mt = 0; mt < 4; ++mt)
                #pragma unroll
                for (int nt = 0; nt < 2; ++nt) {
                    acc[mt][nt] = mfma16(af[mt][0], bf[nt][0], acc[mt][nt]);
                    acc[mt][nt] = mfma16(af[mt][0], bf[nt][1], acc[mt][nt]);
                    acc[mt][nt] = mfma16(af[mt][1], bf[nt][0], acc[mt][nt]);
                }
        }
        __syncthreads();
    }
    // epilogue: q (scaled, with log2e folded), k dense; v written transposed
    #pragma unroll
    for (int mt = 0; mt < 4; ++mt)
        #pragma unroll
        for (int nt = 0; nt < 2; ++nt) {
            int c = col0 + (wn * 2 + nt) * 16 + l15;     // 0..1535
            int which = c >> 9;                          // 0=q,1=k,2=v (block-uniform)
            int head = (c >> 6) & 7, d = c & 63;
            int tokb = row0 + (wm * 4 + mt) * 16 + l4 * 4;
            int b = tokb >> 11, n = tokb & 2047;
            if (which == 2) {
                uint2 pv;
                pv.x = pk_rne(acc[mt][nt][0], acc[mt][nt][1]);
                pv.y = pk_rne(acc[mt][nt][2], acc[mt][nt][3]);
                *(uint2*)&vt[((size_t)((b * 8 + head) * 64 + d)) * 2048 + n] = pv;
            } else {
                unsigned short* dst = which ? kd : qd;
                float s = which ? 1.0f : 0.18033688f;    // 0.125 * log2(e)
                #pragma unroll
                for (int r = 0; r < 4; ++r)
                    dst[(size_t)((b * 8 + head) * 2048 + n + r) * 64 + d] = rne1(acc[mt][nt][r] * s);
            }
        }
}

// ---------------------------------------------------------------------------
// Attention: LDS-staged (round-4 structure), 512 thr = 8 waves (qg2 x kg4),
// 256-key chunks (64 KB LDS), 64 q per block, grid 512 (16 bh x 32 qtiles,
// XCD-swizzled).  S^T = K.Q^T (mfma32, log2e folded into Q -> raw exp2);
// P packed with TRUNCATION; row-sum l computed by MFMA with an all-ones
// A-fragment (sums the rounded P, so the truncation bias cancels in O/l and
// the serial ssum chain disappears).  One LDS merge at the end.
// ---------------------------------------------------------------------------
__global__ __launch_bounds__(512, 4) void attn(const unsigned short* __restrict__ qd,
                                               const unsigned short* __restrict__ kd,
                                               const unsigned short* __restrict__ vt,
                                               unsigned short* __restrict__ Oh,
                                               unsigned short* __restrict__ Ol)
{
    __shared__ __align__(16) char smem[65536];
    char* Kst = smem;            // 32 KB: segs (mt 0..7, s 0..3)
    char* Vst = smem + 32768;    // 32 KB: segs (mtv 0..1, sv 0..15)

    int bid = blockIdx.x;
    int xcd = bid & 7; int rr = bid >> 3;
    int qt = rr & 31; int bhi = rr >> 5;
    int bh = (bhi << 3) | xcd;
    int tid = threadIdx.x, lane = tid & 63, w = tid >> 6;
    int qg = w >> 2, kg = w & 3;
    int l31 = lane & 31, h = lane >> 5;

    // Q^T fragments (B-operand), once from dense qd (pre-scaled, log2e folded)
    short8 qf[4];
    #pragma unroll
    for (int s = 0; s < 4; ++s)
        qf[s] = bcs8(*(const uint4*)(qd + ((size_t)bh * 2048 + qt * 64 + qg * 32 + l31) * 64 + s * 16 + h * 8));

    const uint4 onesu = make_uint4(0x3F803F80u, 0x3F803F80u, 0x3F803F80u, 0x3F803F80u);
    const short8 onesf = bcs8(onesu);

    floatx16 OT[2], OTl;
    #pragma unroll
    for (int i = 0; i < 2; ++i)
        #pragma unroll
        for (int r = 0; r < 16; ++r) OT[i][r] = 0.f;
    #pragma unroll
    for (int r = 0; r < 16; ++r) OTl[r] = 0.f;

    for (int ks0 = 0; ks0 < 2048; ks0 += 256) {
        #pragma unroll
        for (int i = 0; i < 4; ++i) {     // K: 32 segs of 1 KB
            int sid = w * 4 + i; int mt = sid >> 2, s = sid & 3;
            const unsigned short* src = kd + (size_t)(bh * 2048 + ks0 + mt * 32 + l31) * 64 + s * 16 + h * 8;
            glds16(src, Kst + sid * 1024);
        }
        #pragma unroll
        for (int i = 0; i < 4; ++i) {     // V^T: 32 segs
            int sid = w * 4 + i; int mtv = sid >> 4, sv = sid & 15;
            const unsigned short* src = vt + (size_t)(bh * 64 + mtv * 32 + l31) * 2048 + ks0 + sv * 16 + h * 8;
            glds16(src, Vst + sid * 1024);
        }
        __syncthreads();

        #pragma unroll
        for (int u = 0; u < 2; ++u) {     // two 32-key substeps for this wave
            const int mt = kg * 2 + u;
            short8 kf[4];
            #pragma unroll
            for (int s = 0; s < 4; ++s)
                kf[s] = bcs8(*(const uint4*)(Kst + ((mt << 2) + s) * 1024 + (lane << 4)));
            short8 vf[2][2];
            #pragma unroll
            for (int kc = 0; kc < 2; ++kc) {
                int sv = mt * 2 + kc;
                vf[kc][0] = bcs8(*(const uint4*)(Vst + sv * 1024 + (lane << 4)));
                vf[kc][1] = bcs8(*(const uint4*)(Vst + (16 + sv) * 1024 + (lane << 4)));
            }

            floatx16 st;
            #pragma unroll
            for (int r = 0; r < 16; ++r) st[r] = 0.f;
            #pragma unroll
            for (int s = 0; s < 4; ++s) st = mfma32(kf[s], qf[s], st);

            // exp2 (log2e pre-folded), truncation pack (bias cancels via MFMA-l)
            unsigned P2[8];
            #pragma unroll
            for (int s2 = 0; s2 < 8; ++s2)
                P2[s2] = pk_trunc(EXP2(st[2 * s2]), EXP2(st[2 * s2 + 1]));

            #pragma unroll
            for (int kc = 0; kc < 2; ++kc) {
                unsigned X0 = P2[4 * kc + 0], X1 = P2[4 * kc + 1];
                unsigned Y0 = P2[4 * kc + 2], Y1 = P2[4 * kc + 3];
                unsigned Xo0 = __shfl_xor(X0, 32, 64), Xo1 = __shfl_xor(X1, 32, 64);
                unsigned Yo0 = __shfl_xor(Y0, 32, 64), Yo1 = __shfl_xor(Y1, 32, 64);
                uint4 fu;
                fu.x = h ? Yo0 : X0;
                fu.y = h ? Yo1 : X1;
                fu.z = h ? Y0 : Xo0;
                fu.w = h ? Y1 : Xo1;
                short8 pf = bcs8(fu);
                OT[0] = mfma32(vf[kc][0], pf, OT[0]);
                OT[1] = mfma32(vf[kc][1], pf, OT[1]);
                OTl = mfma32(onesf, pf, OTl);   // l += column-sums of rounded P
            }
        }
        __syncthreads();
    }

    // ---- merge partial O/l across the 4 kg waves, per qg ----
    // OTl[0] holds (for every lane) l(q = l31) summed over this wave's keys.
    float* Mq = (float*)smem + qg * 2048;                   // [d(64)][q(32)] 8 KB
    float* Lq = (float*)(smem + 32768) + qg * 64;           // [h(2)][q(32)] dup halves
    float* Tq = (float*)(smem + 32768 + 512) + qg * 2176;   // [q(32)][68]

    if (kg == 3) {
        #pragma unroll
        for (int mtv = 0; mtv < 2; ++mtv)
            #pragma unroll
            for (int r = 0; r < 16; ++r) {
                int d = mtv * 32 + (r & 3) + 8 * (r >> 2) + 4 * h;
                Mq[d * 32 + l31] = OT[mtv][r];
            }
        Lq[h * 32 + l31] = OTl[0];
    }
    __syncthreads();
    if (kg == 2) {
        #pragma unroll
        for (int mtv = 0; mtv < 2; ++mtv)
            #pragma unroll
            for (int r = 0; r < 16; ++r) {
                int d = mtv * 32 + (r & 3) + 8 * (r >> 2) + 4 * h;
                Mq[d * 32 + l31] += OT[mtv][r];
            }
        Lq[h * 32 + l31] += OTl[0];
    }
    __syncthreads();
    if (kg == 1) {
        #pragma unroll
        for (int mtv = 0; mtv < 2; ++mtv)
            #pragma unroll
            for (int r = 0; r < 16; ++r) {
                int d = mtv * 32 + (r & 3) + 8 * (r >> 2) + 4 * h;
                Mq[d * 32 + l31] += OT[mtv][r];
            }
        Lq[h * 32 + l31] += OTl[0];
    }
    __syncthreads();
    if (kg == 0) {
        #pragma unroll
        for (int mtv = 0; mtv < 2; ++mtv)
            #pragma unroll
            for (int r = 0; r < 16; ++r) {
                int d = mtv * 32 + (r & 3) + 8 * (r >> 2) + 4 * h;
                OT[mtv][r] += Mq[d * 32 + l31];
            }
        float inv = 1.f / (Lq[h * 32 + l31] + OTl[0]);      // both halves identical
        #pragma unroll
        for (int mtv = 0; mtv < 2; ++mtv)
            #pragma unroll
            for (int r = 0; r < 16; ++r) {
                int d = mtv * 32 + (r & 3) + 8 * (r >> 2) + 4 * h;
                Tq[l31 * 68 + d] = OT[mtv][r] * inv;
            }
    }
    __syncthreads();
    // all 512 threads: coalesced split-bf16 store of O (flat B,H,N,D)
    {
        int q = tid >> 3, dc = (tid & 7) * 8;               // q 0..63
        const float* T = (const float*)(smem + 32768 + 512) + (q >> 5) * 2176;
        int ql = q & 31;
        float vv[8];
        #pragma unroll
        for (int i = 0; i < 8; ++i) vv[i] = T[ql * 68 + dc + i];
        unsigned hi[4], lo[4];
        #pragma unroll
        for (int i = 0; i < 4; ++i) {
            float a = vv[2 * i], bb = vv[2 * i + 1];
            hi[i] = pk_trunc(a, bb);
            lo[i] = pk_trunc(a - tr16(a), bb - tr16(bb));
        }
        size_t bo = ((size_t)(bh * 2048 + qt * 64 + q)) * 64 + dc;
        *(uint4*)(Oh + bo) = make_uint4(hi[0], hi[1], hi[2], hi[3]);
        *(uint4*)(Ol + bo) = make_uint4(lo[0], lo[1], lo[2], lo[3]);
    }
}

// ---------------------------------------------------------------------------
// GEMM2: out = O(split) @ proj_w(split,T) + bias. BM=64 BN=64 BK=64,
// 256 thr = 4 waves of 32x32. grid (8, 64) = 512 blocks.
// ---------------------------------------------------------------------------
__global__ __launch_bounds__(256, 2) void gemm_proj(const unsigned short* __restrict__ Ah_g,
                                                    const unsigned short* __restrict__ Al_g,
                                                    const unsigned short* __restrict__ wh,
                                                    const unsigned short* __restrict__ wl,
                                                    const float* __restrict__ bias,
                                                    float* __restrict__ out)
{
    __shared__ __align__(16) char smem[32768];
    char* Ah = smem; char* Al = smem + 8192; char* Bh = smem + 16384; char* Bl = smem + 24576;
    const int tid = threadIdx.x, lane = tid & 63, w = tid >> 6;
    const int l15 = lane & 15, l4 = lane >> 4;
    const int row0 = blockIdx.y * 64, col0 = blockIdx.x * 64;
    const int wm = w >> 1, wn = w & 1;

    floatx4 acc[2][2];
    #pragma unroll
    for (int i = 0; i < 2; ++i)
        #pragma unroll
        for (int j = 0; j < 2; ++j)
            #pragma unroll
            for (int r = 0; r < 4; ++r) acc[i][j][r] = 0.f;

    for (int k0 = 0; k0 < 512; k0 += 64) {
        #pragma unroll
        for (int i = 0; i < 8; ++i) {      // 32 segs: 16 A + 16 B
            int sid = w * 8 + i;
            if (sid < 16) {
                int comp = sid & 1, kk = (sid >> 1) & 1, mt = sid >> 2;
                const unsigned short* src = (comp ? Al_g : Ah_g) + (size_t)(row0 + mt * 16 + l15) * 512 + k0 + kk * 32 + l4 * 8;
                glds16(src, (comp ? Al : Ah) + (mt * 2 + kk) * 1024);
            } else {
                int s2 = sid - 16; int comp = s2 & 1, kk = (s2 >> 1) & 1, nt = s2 >> 2;
                const unsigned short* src = (comp ? wl : wh) + (size_t)(col0 + nt * 16 + l15) * 512 + k0 + kk * 32 + l4 * 8;
                glds16(src, (comp ? Bl : Bh) + (nt * 2 + kk) * 1024);
            }
        }
        __syncthreads();
        #pragma unroll
        for (int kk = 0; kk < 2; ++kk) {
            short8 af[2][2], bf[2][2];
            #pragma unroll
            for (int mt = 0; mt < 2; ++mt) {
                int off = (((wm * 2 + mt) * 2 + kk) << 10) + (lane << 4);
                af[mt][0] = bcs8(*(const uint4*)(Ah + off));
                af[mt][1] = bcs8(*(const uint4*)(Al + off));
            }
            #pragma unroll
            for (int nt = 0; nt < 2; ++nt) {
                int off = (((wn * 2 + nt) * 2 + kk) << 10) + (lane << 4);
                bf[nt][0] = bcs8(*(const uint4*)(Bh + off));
                bf[nt][1] = bcs8(*(const uint4*)(Bl + off));
            }
            #pragma unroll
            for (int mt = 0; mt < 2; ++mt)
                #pragma unroll
                for (int nt = 0; nt < 2; ++nt) {
                    acc[mt][nt] = mfma16(af[mt][0], bf[nt][0], acc[mt][nt]);
                    acc[mt][nt] = mfma16(af[mt][0], bf[nt][1], acc[mt][nt]);
                    acc[mt][nt] = mfma16(af[mt][1], bf[nt][0], acc[mt][nt]);
                }
        }
        __syncthreads();
    }
    #pragma unroll
    for (int mt = 0; mt < 2; ++mt)
        #pragma unroll
        for (int nt = 0; nt < 2; ++nt) {
            int c = col0 + (wn * 2 + nt) * 16 + l15;
            float bv = bias[c];
            #pragma unroll
            for (int r = 0; r < 4; ++r) {
                int tok = row0 + (wm * 2 + mt) * 16 + l4 * 4 + r;
                out[(size_t)tok * 512 + c] = acc[mt][nt][r] + bv;
            }
        }
}

// ---------------------------------------------------------------------------
extern "C" void kernel_launch(void* const* d_in, const int* in_sizes, int n_in,
                              void* d_out, int out_size, void* d_ws, size_t ws_size,
                              hipStream_t stream)
{
    const float* x      = (const float*)d_in[0];
    const float* qkv_w  = (const float*)d_in[1];
    const float* proj_w = (const float*)d_in[2];
    const float* proj_b = (const float*)d_in[3];
    float* out = (float*)d_out;

    char* ws = (char*)d_ws;
    unsigned short* qd   = (unsigned short*)ws;                      //  4 MiB
    unsigned short* kd   = (unsigned short*)(ws + 4194304);          //  4 MiB
    unsigned short* vt   = (unsigned short*)(ws + 8388608);          //  4 MiB
    unsigned short* wqh  = (unsigned short*)(ws + 12582912);         // 1.5 MiB
    unsigned short* wql  = (unsigned short*)(ws + 14155776);         // 1.5 MiB
    unsigned short* wph  = (unsigned short*)(ws + 15728640);         // 0.5 MiB
    unsigned short* wpl  = (unsigned short*)(ws + 16252928);         // 0.5 MiB
    unsigned short* Oh   = (unsigned short*)(ws + 16777216);         //  4 MiB
    unsigned short* Ol   = (unsigned short*)(ws + 20971520);         //  4 MiB (end 24 MiB)
    // xh/xl overlay Oh/Ol: consumed by gemm_qkv before attn writes Oh/Ol.
    unsigned short* xh = Oh;
    unsigned short* xl = Ol;

    prep<<<768, 256, 0, stream>>>(qkv_w, proj_w, x, wqh, wql, wph, wpl, xh, xl);
    gemm_qkv<<<dim3(24, 32), 256, 0, stream>>>(xh, xl, wqh, wql, qd, kd, vt);
    attn<<<512, 512, 0, stream>>>(qd, kd, vt, Oh, Ol);
    gemm_proj<<<dim3(8, 64), 256, 0, stream>>>(Oh, Ol, wph, wpl, proj_b, out);
}

// Round 7
// 165.716 us; speedup vs baseline: 1.1610x; 1.0288x over previous
//
#include <hip/hip_runtime.h>
#include <math.h>

constexpr int Bb = 2;
constexpr int Nn = 2048;
constexpr int Cc = 512;
constexpr int Hh = 8;
constexpr int Dd = 64;

typedef short short8 __attribute__((ext_vector_type(8)));
typedef float floatx4 __attribute__((ext_vector_type(4)));
typedef float floatx16 __attribute__((ext_vector_type(16)));

__device__ inline short8 bcs8(uint4 u) { return __builtin_bit_cast(short8, u); }

__device__ inline floatx4 mfma16(short8 a, short8 b, floatx4 c) {
    return __builtin_amdgcn_mfma_f32_16x16x32_bf16(a, b, c, 0, 0, 0);
}
__device__ inline floatx16 mfma32(short8 a, short8 b, floatx16 c) {
    return __builtin_amdgcn_mfma_f32_32x32x16_bf16(a, b, c, 0, 0, 0);
}

// async global->LDS, 16B per lane, dest = uniform base + lane*16
typedef __attribute__((address_space(1))) void gvoid;
typedef __attribute__((address_space(3))) void svoid;
__device__ inline void glds16(const void* g, void* l) {
    __builtin_amdgcn_global_load_lds((const gvoid*)g, (svoid*)l, 16, 0, 0);
}

#if __has_builtin(__builtin_amdgcn_exp2f)
#define EXP2(x) __builtin_amdgcn_exp2f(x)
#else
#define EXP2(x) __expf((x) * 0.69314718056f)
#endif

// pack bf16(a)|bf16(b)<<16, truncation (hi/lo splits: lo compensates hi)
__device__ inline unsigned pk_trunc(float a, float b) {
    return __builtin_amdgcn_perm(__float_as_uint(b), __float_as_uint(a), 0x07060302u);
}
// RNE pack
__device__ inline unsigned pk_rne(float a, float b) {
    unsigned ua = __float_as_uint(a); ua += 0x7fffu + ((ua >> 16) & 1u);
    unsigned ub = __float_as_uint(b); ub += 0x7fffu + ((ub >> 16) & 1u);
    return __builtin_amdgcn_perm(ub, ua, 0x07060302u);
}
__device__ inline unsigned short rne1(float a) {
    unsigned u = __float_as_uint(a); u += 0x7fffu + ((u >> 16) & 1u);
    return (unsigned short)(u >> 16);
}
__device__ inline float tr16(float a) {
    return __uint_as_float(__float_as_uint(a) & 0xffff0000u);
}
__device__ inline void split8(float4 A, float4 B, uint4& hi, uint4& lo) {
    hi = make_uint4(pk_trunc(A.x, A.y), pk_trunc(A.z, A.w),
                    pk_trunc(B.x, B.y), pk_trunc(B.z, B.w));
    lo = make_uint4(pk_trunc(A.x - tr16(A.x), A.y - tr16(A.y)),
                    pk_trunc(A.z - tr16(A.z), A.w - tr16(A.w)),
                    pk_trunc(B.x - tr16(B.x), B.y - tr16(B.y)),
                    pk_trunc(B.z - tr16(B.z), B.w - tr16(B.w)));
}

// ---------------------------------------------------------------------------
// Fused prep: bid<256 -> weight transpose+split; bid>=256 -> x split.
// ---------------------------------------------------------------------------
__global__ __launch_bounds__(256) void prep(const float* __restrict__ qkv_w,
                                            const float* __restrict__ proj_w,
                                            const float* __restrict__ x,
                                            unsigned short* __restrict__ wqh,
                                            unsigned short* __restrict__ wql,
                                            unsigned short* __restrict__ wph,
                                            unsigned short* __restrict__ wpl,
                                            unsigned short* __restrict__ xh,
                                            unsigned short* __restrict__ xl)
{
    __shared__ float Tl[64][68];
    int bid = blockIdx.x;
    if (bid >= 256) {                      // ---- x split ----
        size_t base = ((size_t)(bid - 256) * 256 + threadIdx.x) * 16;
        float4 a = *(const float4*)(x + base);
        float4 b = *(const float4*)(x + base + 4);
        float4 c = *(const float4*)(x + base + 8);
        float4 d = *(const float4*)(x + base + 12);
        uint4 h0, L0, h1, L1;
        split8(a, b, h0, L0); split8(c, d, h1, L1);
        *(uint4*)(xh + base) = h0; *(uint4*)(xh + base + 8) = h1;
        *(uint4*)(xl + base) = L0; *(uint4*)(xl + base + 8) = L1;
        return;
    }
    // ---- weight transpose + split ----
    const float* src; unsigned short *dh, *dlo; int W, f0, k0;
    if (bid < 192) { int kt = bid / 24, ft = bid % 24; W = 1536; src = qkv_w; dh = wqh; dlo = wql; f0 = ft * 64; k0 = kt * 64; }
    else { int b2 = bid - 192; int kt = b2 / 8, ft = b2 % 8; W = 512; src = proj_w; dh = wph; dlo = wpl; f0 = ft * 64; k0 = kt * 64; }
    int t = threadIdx.x;
    {
        int kl = t >> 2, fc = (t & 3) * 16;
        const float* p = src + (size_t)(k0 + kl) * W + f0 + fc;
        #pragma unroll
        for (int i = 0; i < 4; ++i) {
            float4 v = *(const float4*)(p + i * 4);
            Tl[kl][fc + i * 4 + 0] = v.x; Tl[kl][fc + i * 4 + 1] = v.y;
            Tl[kl][fc + i * 4 + 2] = v.z; Tl[kl][fc + i * 4 + 3] = v.w;
        }
    }
    __syncthreads();
    {
        int fl = t >> 2, kc = (t & 3) * 16;
        float v[16];
        #pragma unroll
        for (int i = 0; i < 16; ++i) v[i] = Tl[kc + i][fl];
        unsigned hi[8], lo[8];
        #pragma unroll
        for (int i = 0; i < 8; ++i) {
            float a = v[2 * i], b = v[2 * i + 1];
            hi[i] = pk_trunc(a, b);
            lo[i] = pk_trunc(a - tr16(a), b - tr16(b));
        }
        unsigned short* oh = dh + (size_t)(f0 + fl) * 512 + k0 + kc;
        unsigned short* ol = dlo + (size_t)(f0 + fl) * 512 + k0 + kc;
        *(uint4*)oh = make_uint4(hi[0], hi[1], hi[2], hi[3]);
        *(uint4*)(oh + 8) = make_uint4(hi[4], hi[5], hi[6], hi[7]);
        *(uint4*)ol = make_uint4(lo[0], lo[1], lo[2], lo[3]);
        *(uint4*)(ol + 8) = make_uint4(lo[4], lo[5], lo[6], lo[7]);
    }
}

// ---------------------------------------------------------------------------
// GEMM1: x(split) @ qkv_w(split,T) -> dense qd/kd[bh][n][64] + vt[bh][d][n].
// q pre-scaled by 0.125*log2(e). BM=128 BN=64, software-pipelined BK=32
// stages (double-buffered LDS, one barrier per stage). 256 thr, grid (24,32).
// ---------------------------------------------------------------------------
__global__ __launch_bounds__(256, 3) void gemm_qkv(const unsigned short* __restrict__ xh,
                                                   const unsigned short* __restrict__ xl,
                                                   const unsigned short* __restrict__ wh,
                                                   const unsigned short* __restrict__ wl,
                                                   unsigned short* __restrict__ qd,
                                                   unsigned short* __restrict__ kd,
                                                   unsigned short* __restrict__ vt)
{
    __shared__ __align__(16) char smem[49152];   // 2 x 24 KB buffers
    const int tid = threadIdx.x, lane = tid & 63, w = tid >> 6;
    const int l15 = lane & 15, l4 = lane >> 4;
    const int row0 = blockIdx.y * 128, col0 = blockIdx.x * 64;
    const int wm = w >> 1, wn = w & 1;

    floatx4 acc[4][2];
    #pragma unroll
    for (int i = 0; i < 4; ++i)
        #pragma unroll
        for (int j = 0; j < 2; ++j)
            #pragma unroll
            for (int r = 0; r < 4; ++r) acc[i][j][r] = 0.f;

    auto stage = [&](int k0, char* buf) {
        char* Ah = buf; char* Al = buf + 8192; char* Bh = buf + 16384; char* Bl = buf + 20480;
        #pragma unroll
        for (int i = 0; i < 4; ++i) {            // A: 16 segs (8 mt x hi/lo)
            int sid = w * 4 + i; int mt = sid >> 1, comp = sid & 1;
            const unsigned short* src = (comp ? xl : xh) + (size_t)(row0 + mt * 16 + l15) * 512 + k0 + l4 * 8;
            glds16(src, (comp ? Al : Ah) + mt * 1024);
        }
        #pragma unroll
        for (int i = 0; i < 2; ++i) {            // B: 8 segs (4 nt x hi/lo)
            int sid = w * 2 + i; int nt = sid >> 1, comp = sid & 1;
            const unsigned short* src = (comp ? wl : wh) + (size_t)(col0 + nt * 16 + l15) * 512 + k0 + l4 * 8;
            glds16(src, (comp ? Bl : Bh) + nt * 1024);
        }
    };

    stage(0, smem);
    for (int it = 0; it < 16; ++it) {
        __syncthreads();                          // drains stage(it); prev readers done
        char* buf = smem + (it & 1) * 24576;
        if (it < 15) stage((it + 1) * 32, smem + ((it + 1) & 1) * 24576);
        char* Ah = buf; char* Al = buf + 8192; char* Bh = buf + 16384; char* Bl = buf + 20480;
        short8 af[4][2], bf[2][2];
        #pragma unroll
        for (int mt = 0; mt < 4; ++mt) {
            int off = ((wm * 4 + mt) << 10) + (lane << 4);
            af[mt][0] = bcs8(*(const uint4*)(Ah + off));
            af[mt][1] = bcs8(*(const uint4*)(Al + off));
        }
        #pragma unroll
        for (int nt = 0; nt < 2; ++nt) {
            int off = ((wn * 2 + nt) << 10) + (lane << 4);
            bf[nt][0] = bcs8(*(const uint4*)(Bh + off));
            bf[nt][1] = bcs8(*(const uint4*)(Bl + off));
        }
        #pragma unroll
        for (int mt = 0; mt < 4; ++mt)
            #pragma unroll
            for (int nt = 0; nt < 2; ++nt) {
                acc[mt][nt] = mfma16(af[mt][0], bf[nt][0], acc[mt][nt]);
                acc[mt][nt] = mfma16(af[mt][0], bf[nt][1], acc[mt][nt]);
                acc[mt][nt] = mfma16(af[mt][1], bf[nt][0], acc[mt][nt]);
            }
    }
    // epilogue: q (scaled, with log2e folded), k dense; v written transposed
    #pragma unroll
    for (int mt = 0; mt < 4; ++mt)
        #pragma unroll
        for (int nt = 0; nt < 2; ++nt) {
            int c = col0 + (wn * 2 + nt) * 16 + l15;     // 0..1535
            int which = c >> 9;                          // 0=q,1=k,2=v (block-uniform)
            int head = (c >> 6) & 7, d = c & 63;
            int tokb = row0 + (wm * 4 + mt) * 16 + l4 * 4;
            int b = tokb >> 11, n = tokb & 2047;
            if (which == 2) {
                uint2 pv;
                pv.x = pk_rne(acc[mt][nt][0], acc[mt][nt][1]);
                pv.y = pk_rne(acc[mt][nt][2], acc[mt][nt][3]);
                *(uint2*)&vt[((size_t)((b * 8 + head) * 64 + d)) * 2048 + n] = pv;
            } else {
                unsigned short* dst = which ? kd : qd;
                float s = which ? 1.0f : 0.18033688f;    // 0.125 * log2(e)
                #pragma unroll
                for (int r = 0; r < 4; ++r)
                    dst[(size_t)((b * 8 + head) * 2048 + n + r) * 64 + d] = rne1(acc[mt][nt][r] * s);
            }
        }
}

// ---------------------------------------------------------------------------
// Attention: software-pipelined double-buffered staging. 512 thr = 8 waves
// (qg2 x kg4), 128-key chunks (2 x 32 KB LDS), 64 q per block, grid 512
// (16 bh x 32 qtiles, XCD-swizzled). One barrier per chunk; chunk c+1's
// glds16 issued before computing chunk c, so loads overlap compute.
// S^T = K.Q^T (mfma32, log2e folded into Q -> raw exp2); P packed with
// truncation; l via MFMA with all-ones A-fragment. One LDS merge at end.
// ---------------------------------------------------------------------------
__global__ __launch_bounds__(512, 4) void attn(const unsigned short* __restrict__ qd,
                                               const unsigned short* __restrict__ kd,
                                               const unsigned short* __restrict__ vt,
                                               unsigned short* __restrict__ Oh,
                                               unsigned short* __restrict__ Ol)
{
    __shared__ __align__(16) char smem[65536];   // 2 x [K 16 KB | V 16 KB]

    int bid = blockIdx.x;
    int xcd = bid & 7; int rr = bid >> 3;
    int qt = rr & 31; int bhi = rr >> 5;
    int bh = (bhi << 3) | xcd;
    int tid = threadIdx.x, lane = tid & 63, w = tid >> 6;
    int qg = w >> 2, kg = w & 3;
    int l31 = lane & 31, h = lane >> 5;

    // Q^T fragments (B-operand), once from dense qd (pre-scaled, log2e folded)
    short8 qf[4];
    #pragma unroll
    for (int s = 0; s < 4; ++s)
        qf[s] = bcs8(*(const uint4*)(qd + ((size_t)bh * 2048 + qt * 64 + qg * 32 + l31) * 64 + s * 16 + h * 8));

    const uint4 onesu = make_uint4(0x3F803F80u, 0x3F803F80u, 0x3F803F80u, 0x3F803F80u);
    const short8 onesf = bcs8(onesu);

    floatx16 OT[2], OTl;
    #pragma unroll
    for (int i = 0; i < 2; ++i)
        #pragma unroll
        for (int r = 0; r < 16; ++r) OT[i][r] = 0.f;
    #pragma unroll
    for (int r = 0; r < 16; ++r) OTl[r] = 0.f;

    // stage 128-key chunk c into buf: 32 segs of 1 KB (K 16 + V 16), 4/wave
    auto stage = [&](int c, char* buf) {
        int ks0 = c * 128;
        #pragma unroll
        for (int i = 0; i < 4; ++i) {
            int sid = w * 4 + i;
            if (sid < 16) {                       // K: mt(4) x s(4)
                int mt = sid >> 2, s = sid & 3;
                const unsigned short* src = kd + (size_t)(bh * 2048 + ks0 + mt * 32 + l31) * 64 + s * 16 + h * 8;
                glds16(src, buf + sid * 1024);
            } else {                              // V^T: mtv(2) x sv(8)
                int s2 = sid - 16; int mtv = s2 >> 3, sv = s2 & 7;
                const unsigned short* src = vt + (size_t)(bh * 64 + mtv * 32 + l31) * 2048 + ks0 + sv * 16 + h * 8;
                glds16(src, buf + 16384 + s2 * 1024);
            }
        }
    };

    stage(0, smem);
    for (int c = 0; c < 16; ++c) {
        __syncthreads();                          // drains stage(c); prev buf readers done
        char* cbuf = smem + (c & 1) * 32768;
        if (c < 15) stage(c + 1, smem + ((c + 1) & 1) * 32768);

        char* Kst = cbuf; char* Vst = cbuf + 16384;
        short8 kf[4];
        #pragma unroll
        for (int s = 0; s < 4; ++s)
            kf[s] = bcs8(*(const uint4*)(Kst + ((kg << 2) + s) * 1024 + (lane << 4)));
        short8 vf[2][2];
        #pragma unroll
        for (int kc = 0; kc < 2; ++kc) {
            int sv = kg * 2 + kc;
            vf[kc][0] = bcs8(*(const uint4*)(Vst + sv * 1024 + (lane << 4)));
            vf[kc][1] = bcs8(*(const uint4*)(Vst + (8 + sv) * 1024 + (lane << 4)));
        }

        floatx16 st;
        #pragma unroll
        for (int r = 0; r < 16; ++r) st[r] = 0.f;
        #pragma unroll
        for (int s = 0; s < 4; ++s) st = mfma32(kf[s], qf[s], st);

        // exp2 (log2e pre-folded), truncation pack (bias cancels via MFMA-l)
        unsigned P2[8];
        #pragma unroll
        for (int s2 = 0; s2 < 8; ++s2)
            P2[s2] = pk_trunc(EXP2(st[2 * s2]), EXP2(st[2 * s2 + 1]));

        #pragma unroll
        for (int kc = 0; kc < 2; ++kc) {
            unsigned X0 = P2[4 * kc + 0], X1 = P2[4 * kc + 1];
            unsigned Y0 = P2[4 * kc + 2], Y1 = P2[4 * kc + 3];
            unsigned Xo0 = __shfl_xor(X0, 32, 64), Xo1 = __shfl_xor(X1, 32, 64);
            unsigned Yo0 = __shfl_xor(Y0, 32, 64), Yo1 = __shfl_xor(Y1, 32, 64);
            uint4 fu;
            fu.x = h ? Yo0 : X0;
            fu.y = h ? Yo1 : X1;
            fu.z = h ? Y0 : Xo0;
            fu.w = h ? Y1 : Xo1;
            short8 pf = bcs8(fu);
            OT[0] = mfma32(vf[kc][0], pf, OT[0]);
            OT[1] = mfma32(vf[kc][1], pf, OT[1]);
            OTl = mfma32(onesf, pf, OTl);         // l += column-sums of rounded P
        }
    }

    // ---- merge partial O/l across the 4 kg waves, per qg ----
    float* Mq = (float*)smem + qg * 2048;                   // [d(64)][q(32)] 8 KB
    float* Lq = (float*)(smem + 32768) + qg * 64;           // [h(2)][q(32)] dup halves
    float* Tq = (float*)(smem + 32768 + 512) + qg * 2176;   // [q(32)][68]

    __syncthreads();                              // K-loop fully done before overlay
    if (kg == 3) {
        #pragma unroll
        for (int mtv = 0; mtv < 2; ++mtv)
            #pragma unroll
            for (int r = 0; r < 16; ++r) {
                int d = mtv * 32 + (r & 3) + 8 * (r >> 2) + 4 * h;
                Mq[d * 32 + l31] = OT[mtv][r];
            }
        Lq[h * 32 + l31] = OTl[0];
    }
    __syncthreads();
    if (kg == 2) {
        #pragma unroll
        for (int mtv = 0; mtv < 2; ++mtv)
            #pragma unroll
            for (int r = 0; r < 16; ++r) {
                int d = mtv * 32 + (r & 3) + 8 * (r >> 2) + 4 * h;
                Mq[d * 32 + l31] += OT[mtv][r];
            }
        Lq[h * 32 + l31] += OTl[0];
    }
    __syncthreads();
    if (kg == 1) {
        #pragma unroll
        for (int mtv = 0; mtv < 2; ++mtv)
            #pragma unroll
            for (int r = 0; r < 16; ++r) {
                int d = mtv * 32 + (r & 3) + 8 * (r >> 2) + 4 * h;
                Mq[d * 32 + l31] += OT[mtv][r];
            }
        Lq[h * 32 + l31] += OTl[0];
    }
    __syncthreads();
    if (kg == 0) {
        #pragma unroll
        for (int mtv = 0; mtv < 2; ++mtv)
            #pragma unroll
            for (int r = 0; r < 16; ++r) {
                int d = mtv * 32 + (r & 3) + 8 * (r >> 2) + 4 * h;
                OT[mtv][r] += Mq[d * 32 + l31];
            }
        float inv = 1.f / (Lq[h * 32 + l31] + OTl[0]);      // both halves identical
        #pragma unroll
        for (int mtv = 0; mtv < 2; ++mtv)
            #pragma unroll
            for (int r = 0; r < 16; ++r) {
                int d = mtv * 32 + (r & 3) + 8 * (r >> 2) + 4 * h;
                Tq[l31 * 68 + d] = OT[mtv][r] * inv;
            }
    }
    __syncthreads();
    // all 512 threads: coalesced split-bf16 store of O (flat B,H,N,D)
    {
        int q = tid >> 3, dc = (tid & 7) * 8;               // q 0..63
        const float* T = (const float*)(smem + 32768 + 512) + (q >> 5) * 2176;
        int ql = q & 31;
        float vv[8];
        #pragma unroll
        for (int i = 0; i < 8; ++i) vv[i] = T[ql * 68 + dc + i];
        unsigned hi[4], lo[4];
        #pragma unroll
        for (int i = 0; i < 4; ++i) {
            float a = vv[2 * i], bb = vv[2 * i + 1];
            hi[i] = pk_trunc(a, bb);
            lo[i] = pk_trunc(a - tr16(a), bb - tr16(bb));
        }
        size_t bo = ((size_t)(bh * 2048 + qt * 64 + q)) * 64 + dc;
        *(uint4*)(Oh + bo) = make_uint4(hi[0], hi[1], hi[2], hi[3]);
        *(uint4*)(Ol + bo) = make_uint4(lo[0], lo[1], lo[2], lo[3]);
    }
}

// ---------------------------------------------------------------------------
// GEMM2: out = O(split) @ proj_w(split,T) + bias. BM=64 BN=64, pipelined
// BK=32 stages (2 x 16 KB LDS). 256 thr = 4 waves of 32x32. grid (8,64).
// ---------------------------------------------------------------------------
__global__ __launch_bounds__(256, 2) void gemm_proj(const unsigned short* __restrict__ Ah_g,
                                                    const unsigned short* __restrict__ Al_g,
                                                    const unsigned short* __restrict__ wh,
                                                    const unsigned short* __restrict__ wl,
                                                    const float* __restrict__ bias,
                                                    float* __restrict__ out)
{
    __shared__ __align__(16) char smem[32768];   // 2 x [Ah 4K | Al 4K | Bh 4K | Bl 4K]
    const int tid = threadIdx.x, lane = tid & 63, w = tid >> 6;
    const int l15 = lane & 15, l4 = lane >> 4;
    const int row0 = blockIdx.y * 64, col0 = blockIdx.x * 64;
    const int wm = w >> 1, wn = w & 1;

    floatx4 acc[2][2];
    #pragma unroll
    for (int i = 0; i < 2; ++i)
        #pragma unroll
        for (int j = 0; j < 2; ++j)
            #pragma unroll
            for (int r = 0; r < 4; ++r) acc[i][j][r] = 0.f;

    auto stage = [&](int k0, char* buf) {
        #pragma unroll
        for (int i = 0; i < 4; ++i) {            // 16 segs: 8 A + 8 B
            int sid = w * 4 + i;
            if (sid < 8) {
                int mt = sid >> 1, comp = sid & 1;
                const unsigned short* src = (comp ? Al_g : Ah_g) + (size_t)(row0 + mt * 16 + l15) * 512 + k0 + l4 * 8;
                glds16(src, buf + (comp ? 4096 : 0) + mt * 1024);
            } else {
                int s2 = sid - 8; int nt = s2 >> 1, comp = s2 & 1;
                const unsigned short* src = (comp ? wl : wh) + (size_t)(col0 + nt * 16 + l15) * 512 + k0 + l4 * 8;
                glds16(src, buf + (comp ? 12288 : 8192) + nt * 1024);
            }
        }
    };

    stage(0, smem);
    for (int it = 0; it < 16; ++it) {
        __syncthreads();
        char* buf = smem + (it & 1) * 16384;
        if (it < 15) stage((it + 1) * 32, smem + ((it + 1) & 1) * 16384);
        char* Ah = buf; char* Al = buf + 4096; char* Bh = buf + 8192; char* Bl = buf + 12288;
        short8 af[2][2], bf[2][2];
        #pragma unroll
        for (int mt = 0; mt < 2; ++mt) {
            int off = ((wm * 2 + mt) << 10) + (lane << 4);
            af[mt][0] = bcs8(*(const uint4*)(Ah + off));
            af[mt][1] = bcs8(*(const uint4*)(Al + off));
        }
        #pragma unroll
        for (int nt = 0; nt < 2; ++nt) {
            int off = ((wn * 2 + nt) << 10) + (lane << 4);
            bf[nt][0] = bcs8(*(const uint4*)(Bh + off));
            bf[nt][1] = bcs8(*(const uint4*)(Bl + off));
        }
        #pragma unroll
        for (int mt = 0; mt < 2; ++mt)
            #pragma unroll
            for (int nt = 0; nt < 2; ++nt) {
                acc[mt][nt] = mfma16(af[mt][0], bf[nt][0], acc[mt][nt]);
                acc[mt][nt] = mfma16(af[mt][0], bf[nt][1], acc[mt][nt]);
                acc[mt][nt] = mfma16(af[mt][1], bf[nt][0], acc[mt][nt]);
            }
    }
    #pragma unroll
    for (int mt = 0; mt < 2; ++mt)
        #pragma unroll
        for (int nt = 0; nt < 2; ++nt) {
            int c = col0 + (wn * 2 + nt) * 16 + l15;
            float bv = bias[c];
            #pragma unroll
            for (int r = 0; r < 4; ++r) {
                int tok = row0 + (wm * 2 + mt) * 16 + l4 * 4 + r;
                out[(size_t)tok * 512 + c] = acc[mt][nt][r] + bv;
            }
        }
}

// ---------------------------------------------------------------------------
extern "C" void kernel_launch(void* const* d_in, const int* in_sizes, int n_in,
                              void* d_out, int out_size, void* d_ws, size_t ws_size,
                              hipStream_t stream)
{
    const float* x      = (const float*)d_in[0];
    const float* qkv_w  = (const float*)d_in[1];
    const float* proj_w = (const float*)d_in[2];
    const float* proj_b = (const float*)d_in[3];
    float* out = (float*)d_out;

    char* ws = (char*)d_ws;
    unsigned short* qd   = (unsigned short*)ws;                      //  4 MiB
    unsigned short* kd   = (unsigned short*)(ws + 4194304);          //  4 MiB
    unsigned short* vt   = (unsigned short*)(ws + 8388608);          //  4 MiB
    unsigned short* wqh  = (unsigned short*)(ws + 12582912);         // 1.5 MiB
    unsigned short* wql  = (unsigned short*)(ws + 14155776);         // 1.5 MiB
    unsigned short* wph  = (unsigned short*)(ws + 15728640);         // 0.5 MiB
    unsigned short* wpl  = (unsigned short*)(ws + 16252928);         // 0.5 MiB
    unsigned short* Oh   = (unsigned short*)(ws + 16777216);         //  4 MiB
    unsigned short* Ol   = (unsigned short*)(ws + 20971520);         //  4 MiB (end 24 MiB)
    // xh/xl overlay Oh/Ol: consumed by gemm_qkv before attn writes Oh/Ol.
    unsigned short* xh = Oh;
    unsigned short* xl = Ol;

    prep<<<768, 256, 0, stream>>>(qkv_w, proj_w, x, wqh, wql, wph, wpl, xh, xl);
    gemm_qkv<<<dim3(24, 32), 256, 0, stream>>>(xh, xl, wqh, wql, qd, kd, vt);
    attn<<<512, 512, 0, stream>>>(qd, kd, vt, Oh, Ol);
    gemm_proj<<<dim3(8, 64), 256, 0, stream>>>(Oh, Ol, wph, wpl, proj_b, out);
}